// Round 1
// baseline (39591.809 us; speedup 1.0000x reference)
//
#include <hip/hip_runtime.h>
#include <stdint.h>

#define NB 32          // batch
#define NFR 9          // fragments
#define PF 75          // fragment size
#define PUZS 225
#define DM 768
#define STOK 197
#define NHEAD 12
#define HDIM 64
#define MLPD 3072
#define NLAYER 12
#define NCLSD 1000

// ---------------- Threefry-2x32 (JAX-compatible, 20 rounds) ----------------
__device__ __forceinline__ uint32_t rotl32(uint32_t v, int d){ return (v<<d)|(v>>(32-d)); }

__device__ __forceinline__ void tf2x32(uint32_t k0, uint32_t k1, uint32_t x0, uint32_t x1,
                                       uint32_t& o0, uint32_t& o1)
{
  uint32_t ks2 = k0 ^ k1 ^ 0x1BD11BDAu;
  x0 += k0; x1 += k1;
#define TFR(r) { x0 += x1; x1 = rotl32(x1,(r)); x1 ^= x0; }
  TFR(13) TFR(15) TFR(26) TFR(6)
  x0 += k1;  x1 += ks2 + 1u;
  TFR(17) TFR(29) TFR(16) TFR(24)
  x0 += ks2; x1 += k0 + 2u;
  TFR(13) TFR(15) TFR(26) TFR(6)
  x0 += k0;  x1 += k1 + 3u;
  TFR(17) TFR(29) TFR(16) TFR(24)
  x0 += k1;  x1 += ks2 + 4u;
  TFR(13) TFR(15) TFR(26) TFR(6)
  x0 += ks2; x1 += k0 + 5u;
#undef TFR
  o0 = x0; o1 = x1;
}

// partitionable random_bits (32-bit): bits1 ^ bits2 at 64-bit counter (hi=0, lo=idx)
__device__ __forceinline__ uint32_t tf_bits(uint32_t k0, uint32_t k1, uint32_t idx)
{
  uint32_t a, b; tf2x32(k0, k1, 0u, idx, a, b); return a ^ b;
}

// ---------------- RNG setup: noise->argsort, crop offsets, jitter, target ----------------
__global__ void rng_kernel(int* __restrict__ ids_shuffle, int* __restrict__ offs,
                           int* __restrict__ jitv, float* __restrict__ target_out)
{
  __shared__ float noise[NB*NFR];
  int t = threadIdx.x;
  // key(42) = (0,42); split 3 (foldlike: cipher at (0,i))
  uint32_t kn0,kn1,kc0,kc1,kj0,kj1;
  tf2x32(0u,42u,0u,0u,kn0,kn1);
  tf2x32(0u,42u,0u,1u,kc0,kc1);
  tf2x32(0u,42u,0u,2u,kj0,kj1);

  if (t < NB*NFR) {
    uint32_t bits = tf_bits(kn0, kn1, (uint32_t)t);
    noise[t] = __uint_as_float((bits >> 9) | 0x3f800000u) - 1.0f;
  }
  if (t < NB*NFR*2) { // randint(k_crop,(288,2),0,12): split k_crop, mult = (2^16%12)^2%12 = 4
    uint32_t c10,c11,c20,c21;
    tf2x32(kc0,kc1,0u,0u,c10,c11);
    tf2x32(kc0,kc1,0u,1u,c20,c21);
    uint32_t hb = tf_bits(c10,c11,(uint32_t)t);
    uint32_t lb = tf_bits(c20,c21,(uint32_t)t);
    offs[t] = (int)((((hb % 12u) * 4u) + (lb % 12u)) % 12u);
  }
  if (t < NB*NFR*3) { // randint(k_jit,(288,3,1,1),-2,3): span 5, mult = 1
    uint32_t c10,c11,c20,c21;
    tf2x32(kj0,kj1,0u,0u,c10,c11);
    tf2x32(kj0,kj1,0u,1u,c20,c21);
    uint32_t hb = tf_bits(c10,c11,(uint32_t)t);
    uint32_t lb = tf_bits(c20,c21,(uint32_t)t);
    jitv[t] = -2 + (int)(((hb % 5u) + (lb % 5u)) % 5u);
  }
  __syncthreads();
  if (t < NB) {
    float v[NFR]; int idx[NFR];
    for (int i = 0; i < NFR; i++) { v[i] = noise[t*NFR + i]; idx[i] = i; }
    // stable insertion sort ascending == jnp.argsort
    for (int i = 1; i < NFR; i++) {
      float kv = v[i]; int ki = idx[i]; int j = i - 1;
      while (j >= 0 && v[j] > kv) { v[j+1] = v[j]; idx[j+1] = idx[j]; j--; }
      v[j+1] = kv; idx[j+1] = ki;
    }
    int restore[NFR];
    for (int k = 0; k < NFR; k++) { ids_shuffle[t*NFR + k] = idx[k]; restore[idx[k]] = k; }
    for (int f = 0; f < NFR; f++) {
      int r = restore[f];
      target_out[(t*NFR + f)*2 + 0] = (float)(r / 3);
      target_out[(t*NFR + f)*2 + 1] = (float)(r % 3);
    }
  }
}

// ---------------- Augment: crop 64 -> bilinear 75 -> jitter -> clip -> normalize ----------------
__launch_bounds__(256)
__global__ void augment_kernel(const float* __restrict__ x, const int* __restrict__ ids_shuffle,
                               const int* __restrict__ offs, const int* __restrict__ jitv,
                               float* __restrict__ img)
{
  int bid = blockIdx.x;          // m*3 + c
  int m = bid / 3, c = bid % 3;
  int n = m / NFR, k = m % NFR;
  int fs = ids_shuffle[m];       // source fragment id
  int si = fs / 3, sj = fs % 3;
  int gi = k / 3,  gj = k % 3;
  int oy = offs[2*m], ox = offs[2*m+1];
  float jv = (float)jitv[3*m + c];
  const float* src = x + (((size_t)n*3 + c)*PUZS + (size_t)si*PF)*PUZS + (size_t)sj*PF;

  __shared__ float vals[PF*PF];
  __shared__ double dred[256];
  int tid = threadIdx.x;
  const float sc = 64.0f / 75.0f;

  double lsum = 0.0;
  for (int p = tid; p < PF*PF; p += 256) {
    int py = p / PF, px = p % PF;
    float yy = (py + 0.5f)*sc - 0.5f;
    float xx = (px + 0.5f)*sc - 0.5f;
    int y0 = (int)floorf(yy); float fy = yy - (float)y0;
    int x0 = (int)floorf(xx); float fx = xx - (float)x0;
    int y0c = min(max(y0, 0), 63), y1c = min(max(y0+1, 0), 63);
    int x0c = min(max(x0, 0), 63), x1c = min(max(x0+1, 0), 63);
    const float* r0 = src + (size_t)(oy + y0c)*PUZS + ox;
    const float* r1 = src + (size_t)(oy + y1c)*PUZS + ox;
    float v00 = r0[x0c], v01 = r0[x1c], v10 = r1[x0c], v11 = r1[x1c];
    float v = (1.f-fy)*((1.f-fx)*v00 + fx*v01) + fy*((1.f-fx)*v10 + fx*v11);
    v = fminf(fmaxf(v + jv, 0.f), 255.f);
    vals[p] = v;
    lsum += (double)v;
  }
  dred[tid] = lsum; __syncthreads();
  for (int s = 128; s > 0; s >>= 1) { if (tid < s) dred[tid] += dred[tid+s]; __syncthreads(); }
  double mean = dred[0] / (double)(PF*PF);
  __syncthreads();
  double lss = 0.0;
  for (int p = tid; p < PF*PF; p += 256) { double d = (double)vals[p] - mean; lss += d*d; }
  dred[tid] = lss; __syncthreads();
  for (int s = 128; s > 0; s >>= 1) { if (tid < s) dred[tid] += dred[tid+s]; __syncthreads(); }
  double var = dred[0] / (double)(PF*PF - 1);
  float sdev = (float)sqrt(var);
  if (sdev == 0.f) sdev = 1.f;
  float mf = (float)mean;
  float* dst = img + (((size_t)n*3 + c)*PUZS + (size_t)gi*PF)*PUZS + (size_t)gj*PF;
  for (int p = tid; p < PF*PF; p += 256)
    dst[(size_t)(p/PF)*PUZS + (p%PF)] = (vals[p] - mf) / sdev;
}

// ---------------- Patch gather ----------------
__global__ void gather_patches(const float* __restrict__ img, float* __restrict__ Xp)
{
  int tg = blockIdx.x;           // n*196 + t
  int n = tg / 196, t = tg % 196;
  int ti = t / 14, tj = t % 14;
  for (int d = threadIdx.x; d < DM; d += 256) {
    int c = d >> 8, r = (d >> 4) & 15, col = d & 15;
    Xp[(size_t)tg*DM + d] =
      img[(((size_t)n*3 + c)*PUZS + (size_t)(ti*16 + r))*PUZS + (tj*16 + col)];
  }
}

__global__ void assemble_tok(const float* __restrict__ Ctmp, const float* __restrict__ patch_b,
                             const float* __restrict__ cls_tok, const float* __restrict__ pos,
                             float* __restrict__ tok)
{
  int row = blockIdx.x;          // n*197 + t
  int n = row / STOK, t = row % STOK;
  float* o = tok + (size_t)row*DM;
  if (t == 0) {
    for (int i = threadIdx.x; i < DM; i += 256) o[i] = cls_tok[i] + pos[i];
  } else {
    const float* cm = Ctmp + ((size_t)n*196 + (t-1))*DM;
    const float* pp = pos + (size_t)t*DM;
    for (int i = threadIdx.x; i < DM; i += 256) o[i] = cm[i] + patch_b[i] + pp[i];
  }
}

// ---------------- LayerNorm (row-wise, two-pass) ----------------
__launch_bounds__(256)
__global__ void ln_kernel(const float* __restrict__ X, size_t xstride, float* __restrict__ Y,
                          const float* __restrict__ g, const float* __restrict__ b)
{
  __shared__ float buf[DM];
  __shared__ float red[256];
  int r = blockIdx.x, tid = threadIdx.x;
  const float* xr = X + (size_t)r * xstride;
  float lsum = 0.f;
  for (int i = tid; i < DM; i += 256) { float v = xr[i]; buf[i] = v; lsum += v; }
  red[tid] = lsum; __syncthreads();
  for (int s = 128; s > 0; s >>= 1) { if (tid < s) red[tid] += red[tid+s]; __syncthreads(); }
  float mean = red[0] / (float)DM;
  __syncthreads();
  float lss = 0.f;
  for (int i = tid; i < DM; i += 256) { float d = buf[i] - mean; lss += d*d; }
  red[tid] = lss; __syncthreads();
  for (int s = 128; s > 0; s >>= 1) { if (tid < s) red[tid] += red[tid+s]; __syncthreads(); }
  float rstd = rsqrtf(red[0] / (float)DM + 1e-6f);
  float* yr = Y + (size_t)r * DM;
  for (int i = tid; i < DM; i += 256) yr[i] = (buf[i] - mean) * rstd * g[i] + b[i];
}

// ---------------- Generic fp32 GEMM: C = act(A@B + bias + addsrc) ----------------
// ACT: 0 none, 1 gelu(exact erf), 2 relu
template<int ACT>
__launch_bounds__(256)
__global__ void gemm_f32(const float* __restrict__ A, const float* __restrict__ B,
                         const float* __restrict__ bias, const float* __restrict__ addsrc,
                         float* __restrict__ C, int M, int N, int K)
{
  __shared__ float As[8][132];   // [k][m]
  __shared__ float Bs[8][132];   // [k][n]
  int tid = threadIdx.x;
  int tx = tid & 15, ty = tid >> 4;
  int bm = blockIdx.y * 128, bn = blockIdx.x * 128;
  float acc[8][8];
  #pragma unroll
  for (int i = 0; i < 8; i++)
    #pragma unroll
    for (int j = 0; j < 8; j++) acc[i][j] = 0.f;

  for (int k0 = 0; k0 < K; k0 += 8) {
    #pragma unroll
    for (int i = 0; i < 4; i++) {
      int idx = tid + i*256;
      int m = idx >> 3, k = idx & 7;
      int gm = bm + m, gk = k0 + k;
      As[k][m] = (gm < M && gk < K) ? A[(size_t)gm*K + gk] : 0.f;
      int kb = idx >> 7, nn = idx & 127;
      int gk2 = k0 + kb, gn = bn + nn;
      Bs[kb][nn] = (gk2 < K && gn < N) ? B[(size_t)gk2*N + gn] : 0.f;
    }
    __syncthreads();
    #pragma unroll
    for (int kk = 0; kk < 8; kk++) {
      float a[8], bb[8];
      #pragma unroll
      for (int i = 0; i < 8; i++) a[i] = As[kk][ty*8 + i];
      #pragma unroll
      for (int j = 0; j < 8; j++) bb[j] = Bs[kk][tx*8 + j];
      #pragma unroll
      for (int i = 0; i < 8; i++)
        #pragma unroll
        for (int j = 0; j < 8; j++) acc[i][j] += a[i] * bb[j];
    }
    __syncthreads();
  }

  #pragma unroll
  for (int i = 0; i < 8; i++) {
    int gm = bm + ty*8 + i;
    if (gm >= M) continue;
    #pragma unroll
    for (int j = 0; j < 8; j++) {
      int gn = bn + tx*8 + j;
      if (gn >= N) continue;
      float v = acc[i][j];
      if (bias)   v += bias[gn];
      if (addsrc) v += addsrc[(size_t)gm*N + gn];
      if (ACT == 1) v = 0.5f * v * (1.f + erff(v * 0.7071067811865475f));
      if (ACT == 2) v = fmaxf(v, 0.f);
      C[(size_t)gm*N + gn] = v;
    }
  }
}

// ---------------- Fused attention per (n, head) ----------------
__launch_bounds__(1024)
__global__ void attn_kernel(const float* __restrict__ QKV, float* __restrict__ O)
{
  __shared__ float Ks[STOK*65];
  __shared__ float Vs[STOK*65];
  __shared__ float Ps[16*200];
  int blk = blockIdx.x;
  int n = blk / NHEAD, h = blk % NHEAD;
  const float* base = QKV + (size_t)n*STOK*(3*DM) + (size_t)h*HDIM;
  int tid = threadIdx.x;
  for (int idx = tid; idx < STOK*HDIM; idx += 1024) {
    int j = idx >> 6, d = idx & 63;
    const float* row = base + (size_t)j*(3*DM);
    Ks[j*65 + d] = row[DM + d];
    Vs[j*65 + d] = row[2*DM + d];
  }
  __syncthreads();
  int w = tid >> 6, lane = tid & 63;
  for (int r = w; r < STOK; r += 16) {
    float qv = base[(size_t)r*(3*DM) + lane];
    float s0 = 0.f, s1 = 0.f, s2 = 0.f, s3 = 0.f;
    int j3 = 192 + lane;
    int j3c = (j3 < STOK) ? j3 : (STOK - 1);
    #pragma unroll 16
    for (int d = 0; d < 64; d++) {
      float qd = __shfl(qv, d, 64);
      s0 += qd * Ks[lane*65 + d];
      s1 += qd * Ks[(64 + lane)*65 + d];
      s2 += qd * Ks[(128 + lane)*65 + d];
      s3 += qd * Ks[j3c*65 + d];
    }
    const float scale = 0.125f;
    s0 *= scale; s1 *= scale; s2 *= scale; s3 *= scale;
    if (j3 >= STOK) s3 = -INFINITY;
    float mx = fmaxf(fmaxf(s0, s1), fmaxf(s2, s3));
    #pragma unroll
    for (int o = 32; o > 0; o >>= 1) mx = fmaxf(mx, __shfl_xor(mx, o, 64));
    float p0 = expf(s0 - mx), p1 = expf(s1 - mx), p2 = expf(s2 - mx);
    float p3 = (j3 < STOK) ? expf(s3 - mx) : 0.f;
    float sm = p0 + p1 + p2 + p3;
    #pragma unroll
    for (int o = 32; o > 0; o >>= 1) sm += __shfl_xor(sm, o, 64);
    float inv = 1.f / sm;
    float* pr = Ps + w*200;
    pr[lane] = p0*inv; pr[64 + lane] = p1*inv; pr[128 + lane] = p2*inv;
    if (j3 < STOK) pr[j3] = p3*inv;
    __builtin_amdgcn_wave_barrier();
    float oa = 0.f;
    #pragma unroll 4
    for (int j = 0; j < STOK; j++) oa += pr[j] * Vs[j*65 + lane];
    O[((size_t)n*STOK + r)*DM + (size_t)h*HDIM + lane] = oa;
    __builtin_amdgcn_wave_barrier();
  }
}

// ---------------- Host launch ----------------
extern "C" void kernel_launch(void* const* d_in, const int* in_sizes, int n_in,
                              void* d_out, int out_size, void* d_ws, size_t ws_size,
                              hipStream_t stream)
{
  (void)in_sizes; (void)n_in; (void)out_size; (void)ws_size;
  const float* x       = (const float*)d_in[0];
  const float* patch_w = (const float*)d_in[1];
  const float* patch_b = (const float*)d_in[2];
  const float* cls_tok = (const float*)d_in[3];
  const float* pos     = (const float*)d_in[4];
  const float* ln1_s   = (const float*)d_in[5];
  const float* ln1_b   = (const float*)d_in[6];
  const float* qkv_w   = (const float*)d_in[7];
  const float* qkv_b   = (const float*)d_in[8];
  const float* proj_w  = (const float*)d_in[9];
  const float* proj_b  = (const float*)d_in[10];
  const float* ln2_s   = (const float*)d_in[11];
  const float* ln2_b   = (const float*)d_in[12];
  const float* mlp1_w  = (const float*)d_in[13];
  const float* mlp1_b  = (const float*)d_in[14];
  const float* mlp2_w  = (const float*)d_in[15];
  const float* mlp2_b  = (const float*)d_in[16];
  const float* lnf_s   = (const float*)d_in[17];
  const float* lnf_b   = (const float*)d_in[18];
  const float* head_w  = (const float*)d_in[19];
  const float* head_b  = (const float*)d_in[20];
  const float* fc1_w   = (const float*)d_in[21];
  const float* fc1_b   = (const float*)d_in[22];
  const float* fc2_w   = (const float*)d_in[23];
  const float* fc2_b   = (const float*)d_in[24];
  float* out = (float*)d_out;

  const int ROWS = NB * STOK;            // 6304
  float* ws   = (float*)d_ws;
  float* tok  = ws;                       // 6304*768
  float* H    = ws + (size_t)ROWS*DM;     // 6304*768 (also Xp, also attention O)
  float* R2   = H  + (size_t)ROWS*DM;     // 6304*3072 arena
  float* img  = R2;                       // 32*3*225*225 = 3,037,500
  float* Ctmp = R2 + 3200000;             // 6272*768
  float* QKV  = R2;                       // 6304*2304
  float* Mb   = R2;                       // 6304*3072
  float* smallf = R2 + (size_t)ROWS*MLPD;
  int*   ids  = (int*)smallf;             // 288
  int*   offs = ids + NB*NFR;             // 576
  int*   jitv = offs + NB*NFR*2;          // 864
  float* clsb = smallf + 2048;            // 32*768
  float* feat = clsb + NB*DM;             // 32*1000
  float* f1   = feat + NB*NCLSD;          // 32*1000

  // 1. RNG + target
  rng_kernel<<<1, 1024, 0, stream>>>(ids, offs, jitv, out + NB*NFR*2);
  // 2. augmentation -> img
  augment_kernel<<<NB*NFR*3, 256, 0, stream>>>(x, ids, offs, jitv, img);
  // 3. patchify -> Xp (in H)
  gather_patches<<<NB*196, 256, 0, stream>>>(img, H);
  // 4. patch embed GEMM
  {
    dim3 g((DM + 127)/128, (NB*196 + 127)/128);
    gemm_f32<0><<<g, 256, 0, stream>>>(H, patch_w, nullptr, nullptr, Ctmp, NB*196, DM, DM);
  }
  // 5. assemble tokens (+cls, +pos)
  assemble_tok<<<ROWS, 256, 0, stream>>>(Ctmp, patch_b, cls_tok, pos, tok);

  // 6. transformer layers
  dim3 gqkv((3*DM + 127)/128, (ROWS + 127)/128);
  dim3 gd  ((DM   + 127)/128, (ROWS + 127)/128);
  dim3 gmlp((MLPD + 127)/128, (ROWS + 127)/128);
  for (int l = 0; l < NLAYER; l++) {
    ln_kernel<<<ROWS, 256, 0, stream>>>(tok, DM, H, ln1_s + (size_t)l*DM, ln1_b + (size_t)l*DM);
    gemm_f32<0><<<gqkv, 256, 0, stream>>>(H, qkv_w + (size_t)l*DM*3*DM, qkv_b + (size_t)l*3*DM,
                                          nullptr, QKV, ROWS, 3*DM, DM);
    attn_kernel<<<NB*NHEAD, 1024, 0, stream>>>(QKV, H);
    gemm_f32<0><<<gd, 256, 0, stream>>>(H, proj_w + (size_t)l*DM*DM, proj_b + (size_t)l*DM,
                                        tok, tok, ROWS, DM, DM);
    ln_kernel<<<ROWS, 256, 0, stream>>>(tok, DM, H, ln2_s + (size_t)l*DM, ln2_b + (size_t)l*DM);
    gemm_f32<1><<<gmlp, 256, 0, stream>>>(H, mlp1_w + (size_t)l*DM*MLPD, mlp1_b + (size_t)l*MLPD,
                                          nullptr, Mb, ROWS, MLPD, DM);
    gemm_f32<0><<<gd, 256, 0, stream>>>(Mb, mlp2_w + (size_t)l*MLPD*DM, mlp2_b + (size_t)l*DM,
                                        tok, tok, ROWS, DM, MLPD);
  }

  // 7. final LN on cls rows
  ln_kernel<<<NB, 256, 0, stream>>>(tok, (size_t)STOK*DM, clsb, lnf_s, lnf_b);
  // 8. head
  {
    dim3 g((NCLSD + 127)/128, 1);
    gemm_f32<0><<<g, 256, 0, stream>>>(clsb, head_w, head_b, nullptr, feat, NB, NCLSD, DM);
    gemm_f32<2><<<g, 256, 0, stream>>>(feat, fc1_w, fc1_b, nullptr, f1, NB, NCLSD, NCLSD);
    dim3 go(1, 1);
    gemm_f32<0><<<go, 256, 0, stream>>>(f1, fc2_w, fc2_b, nullptr, out, NB, 2*NFR, NCLSD);
  }
}

// Round 2
// 9671.038 us; speedup vs baseline: 4.0939x; 4.0939x over previous
//
#include <hip/hip_runtime.h>
#include <stdint.h>

#define NB 32          // batch
#define NFR 9          // fragments
#define PF 75          // fragment size
#define PUZS 225
#define DM 768
#define STOK 197
#define NHEAD 12
#define HDIM 64
#define MLPD 3072
#define NLAYER 12
#define NCLSD 1000

typedef __bf16 bf16x8 __attribute__((ext_vector_type(8)));
typedef float f32x4 __attribute__((ext_vector_type(4)));

// ---------------- Threefry-2x32 (JAX-compatible, 20 rounds) ----------------
__device__ __forceinline__ uint32_t rotl32(uint32_t v, int d){ return (v<<d)|(v>>(32-d)); }

__device__ __forceinline__ void tf2x32(uint32_t k0, uint32_t k1, uint32_t x0, uint32_t x1,
                                       uint32_t& o0, uint32_t& o1)
{
  uint32_t ks2 = k0 ^ k1 ^ 0x1BD11BDAu;
  x0 += k0; x1 += k1;
#define TFR(r) { x0 += x1; x1 = rotl32(x1,(r)); x1 ^= x0; }
  TFR(13) TFR(15) TFR(26) TFR(6)
  x0 += k1;  x1 += ks2 + 1u;
  TFR(17) TFR(29) TFR(16) TFR(24)
  x0 += ks2; x1 += k0 + 2u;
  TFR(13) TFR(15) TFR(26) TFR(6)
  x0 += k0;  x1 += k1 + 3u;
  TFR(17) TFR(29) TFR(16) TFR(24)
  x0 += k1;  x1 += ks2 + 4u;
  TFR(13) TFR(15) TFR(26) TFR(6)
  x0 += ks2; x1 += k0 + 5u;
#undef TFR
  o0 = x0; o1 = x1;
}

__device__ __forceinline__ uint32_t tf_bits(uint32_t k0, uint32_t k1, uint32_t idx)
{
  uint32_t a, b; tf2x32(k0, k1, 0u, idx, a, b); return a ^ b;
}

// ---------------- RNG setup: noise->argsort, crop offsets, jitter, target ----------------
__global__ void rng_kernel(int* __restrict__ ids_shuffle, int* __restrict__ offs,
                           int* __restrict__ jitv, float* __restrict__ target_out)
{
  __shared__ float noise[NB*NFR];
  int t = threadIdx.x;
  uint32_t kn0,kn1,kc0,kc1,kj0,kj1;
  tf2x32(0u,42u,0u,0u,kn0,kn1);
  tf2x32(0u,42u,0u,1u,kc0,kc1);
  tf2x32(0u,42u,0u,2u,kj0,kj1);

  if (t < NB*NFR) {
    uint32_t bits = tf_bits(kn0, kn1, (uint32_t)t);
    noise[t] = __uint_as_float((bits >> 9) | 0x3f800000u) - 1.0f;
  }
  if (t < NB*NFR*2) {
    uint32_t c10,c11,c20,c21;
    tf2x32(kc0,kc1,0u,0u,c10,c11);
    tf2x32(kc0,kc1,0u,1u,c20,c21);
    uint32_t hb = tf_bits(c10,c11,(uint32_t)t);
    uint32_t lb = tf_bits(c20,c21,(uint32_t)t);
    offs[t] = (int)((((hb % 12u) * 4u) + (lb % 12u)) % 12u);
  }
  if (t < NB*NFR*3) {
    uint32_t c10,c11,c20,c21;
    tf2x32(kj0,kj1,0u,0u,c10,c11);
    tf2x32(kj0,kj1,0u,1u,c20,c21);
    uint32_t hb = tf_bits(c10,c11,(uint32_t)t);
    uint32_t lb = tf_bits(c20,c21,(uint32_t)t);
    jitv[t] = -2 + (int)(((hb % 5u) + (lb % 5u)) % 5u);
  }
  __syncthreads();
  if (t < NB) {
    float v[NFR]; int idx[NFR];
    for (int i = 0; i < NFR; i++) { v[i] = noise[t*NFR + i]; idx[i] = i; }
    for (int i = 1; i < NFR; i++) {
      float kv = v[i]; int ki = idx[i]; int j = i - 1;
      while (j >= 0 && v[j] > kv) { v[j+1] = v[j]; idx[j+1] = idx[j]; j--; }
      v[j+1] = kv; idx[j+1] = ki;
    }
    int restore[NFR];
    for (int k = 0; k < NFR; k++) { ids_shuffle[t*NFR + k] = idx[k]; restore[idx[k]] = k; }
    for (int f = 0; f < NFR; f++) {
      int r = restore[f];
      target_out[(t*NFR + f)*2 + 0] = (float)(r / 3);
      target_out[(t*NFR + f)*2 + 1] = (float)(r % 3);
    }
  }
}

// ---------------- Augment ----------------
__launch_bounds__(256)
__global__ void augment_kernel(const float* __restrict__ x, const int* __restrict__ ids_shuffle,
                               const int* __restrict__ offs, const int* __restrict__ jitv,
                               float* __restrict__ img)
{
  int bid = blockIdx.x;          // m*3 + c
  int m = bid / 3, c = bid % 3;
  int n = m / NFR, k = m % NFR;
  int fs = ids_shuffle[m];
  int si = fs / 3, sj = fs % 3;
  int gi = k / 3,  gj = k % 3;
  int oy = offs[2*m], ox = offs[2*m+1];
  float jv = (float)jitv[3*m + c];
  const float* src = x + (((size_t)n*3 + c)*PUZS + (size_t)si*PF)*PUZS + (size_t)sj*PF;

  __shared__ float vals[PF*PF];
  __shared__ double dred[256];
  int tid = threadIdx.x;
  const float sc = 64.0f / 75.0f;

  double lsum = 0.0;
  for (int p = tid; p < PF*PF; p += 256) {
    int py = p / PF, px = p % PF;
    float yy = (py + 0.5f)*sc - 0.5f;
    float xx = (px + 0.5f)*sc - 0.5f;
    int y0 = (int)floorf(yy); float fy = yy - (float)y0;
    int x0 = (int)floorf(xx); float fx = xx - (float)x0;
    int y0c = min(max(y0, 0), 63), y1c = min(max(y0+1, 0), 63);
    int x0c = min(max(x0, 0), 63), x1c = min(max(x0+1, 0), 63);
    const float* r0 = src + (size_t)(oy + y0c)*PUZS + ox;
    const float* r1 = src + (size_t)(oy + y1c)*PUZS + ox;
    float v00 = r0[x0c], v01 = r0[x1c], v10 = r1[x0c], v11 = r1[x1c];
    float v = (1.f-fy)*((1.f-fx)*v00 + fx*v01) + fy*((1.f-fx)*v10 + fx*v11);
    v = fminf(fmaxf(v + jv, 0.f), 255.f);
    vals[p] = v;
    lsum += (double)v;
  }
  dred[tid] = lsum; __syncthreads();
  for (int s = 128; s > 0; s >>= 1) { if (tid < s) dred[tid] += dred[tid+s]; __syncthreads(); }
  double mean = dred[0] / (double)(PF*PF);
  __syncthreads();
  double lss = 0.0;
  for (int p = tid; p < PF*PF; p += 256) { double d = (double)vals[p] - mean; lss += d*d; }
  dred[tid] = lss; __syncthreads();
  for (int s = 128; s > 0; s >>= 1) { if (tid < s) dred[tid] += dred[tid+s]; __syncthreads(); }
  double var = dred[0] / (double)(PF*PF - 1);
  float sdev = (float)sqrt(var);
  if (sdev == 0.f) sdev = 1.f;
  float mf = (float)mean;
  float* dst = img + (((size_t)n*3 + c)*PUZS + (size_t)gi*PF)*PUZS + (size_t)gj*PF;
  for (int p = tid; p < PF*PF; p += 256)
    dst[(size_t)(p/PF)*PUZS + (p%PF)] = (vals[p] - mf) / sdev;
}

// ---------------- Patch gather (fp32 img -> bf16 Xp) ----------------
__global__ void gather_patches(const float* __restrict__ img, __bf16* __restrict__ Xp)
{
  int tg = blockIdx.x;           // n*196 + t
  int n = tg / 196, t = tg % 196;
  int ti = t / 14, tj = t % 14;
  for (int d = threadIdx.x; d < DM; d += 256) {
    int c = d >> 8, r = (d >> 4) & 15, col = d & 15;
    Xp[(size_t)tg*DM + d] = (__bf16)
      img[(((size_t)n*3 + c)*PUZS + (size_t)(ti*16 + r))*PUZS + (tj*16 + col)];
  }
}

__global__ void assemble_tok(const float* __restrict__ Ctmp, const float* __restrict__ patch_b,
                             const float* __restrict__ cls_tok, const float* __restrict__ pos,
                             float* __restrict__ tok)
{
  int row = blockIdx.x;          // n*197 + t
  int n = row / STOK, t = row % STOK;
  float* o = tok + (size_t)row*DM;
  if (t == 0) {
    for (int i = threadIdx.x; i < DM; i += 256) o[i] = cls_tok[i] + pos[i];
  } else {
    const float* cm = Ctmp + ((size_t)n*196 + (t-1))*DM;
    const float* pp = pos + (size_t)t*DM;
    for (int i = threadIdx.x; i < DM; i += 256) o[i] = cm[i] + patch_b[i] + pp[i];
  }
}

// ---------------- LayerNorm (templated output dtype) ----------------
template<typename OT>
__launch_bounds__(256)
__global__ void ln_kernel(const float* __restrict__ X, size_t xstride, OT* __restrict__ Y,
                          const float* __restrict__ g, const float* __restrict__ b)
{
  __shared__ float buf[DM];
  __shared__ float red[256];
  int r = blockIdx.x, tid = threadIdx.x;
  const float* xr = X + (size_t)r * xstride;
  float lsum = 0.f;
  for (int i = tid; i < DM; i += 256) { float v = xr[i]; buf[i] = v; lsum += v; }
  red[tid] = lsum; __syncthreads();
  for (int s = 128; s > 0; s >>= 1) { if (tid < s) red[tid] += red[tid+s]; __syncthreads(); }
  float mean = red[0] / (float)DM;
  __syncthreads();
  float lss = 0.f;
  for (int i = tid; i < DM; i += 256) { float d = buf[i] - mean; lss += d*d; }
  red[tid] = lss; __syncthreads();
  for (int s = 128; s > 0; s >>= 1) { if (tid < s) red[tid] += red[tid+s]; __syncthreads(); }
  float rstd = rsqrtf(red[0] / (float)DM + 1e-6f);
  OT* yr = Y + (size_t)r * DM;
  for (int i = tid; i < DM; i += 256) yr[i] = (OT)((buf[i] - mean) * rstd * g[i] + b[i]);
}

// ---------------- Transpose+convert: fp32 [K][N] -> bf16 [N][K] ----------------
__launch_bounds__(256)
__global__ void convT(const float* __restrict__ src, __bf16* __restrict__ dst, int K, int N)
{
  __shared__ float t[32][33];
  int k0 = blockIdx.y*32, n0 = blockIdx.x*32;
  int tx = threadIdx.x, ty = threadIdx.y; // 32x8
  #pragma unroll
  for (int i = 0; i < 32; i += 8)
    t[ty+i][tx] = src[(size_t)(k0+ty+i)*N + n0+tx];
  __syncthreads();
  #pragma unroll
  for (int i = 0; i < 32; i += 8)
    dst[(size_t)(n0+ty+i)*K + k0+tx] = (__bf16)t[tx][ty+i];
}

// ---------------- bf16 MFMA GEMM: C = act(A @ BT^T + bias [+ addsrc]) ----------------
// A [Mpad][K] bf16 row-major, BT [N][K] bf16 row-major. 128x128 tile, BK=32.
// ACT: 0 none, 1 gelu(exact), 2 relu. OT: float or __bf16.
template<int ACT, bool ADD, typename OT>
__launch_bounds__(256)
__global__ void gemm_bf16(const __bf16* __restrict__ A, const __bf16* __restrict__ BT,
                          const float* __restrict__ bias, const float* __restrict__ addsrc,
                          OT* __restrict__ C, int M, int N, int K)
{
  __shared__ __attribute__((aligned(16))) __bf16 As[128*32];
  __shared__ __attribute__((aligned(16))) __bf16 Bs[128*32];
  const int tid = threadIdx.x;
  const int wave = tid >> 6, lane = tid & 63;
  const int quad = lane >> 4, l16 = lane & 15;
  const int wm = (wave & 1) << 6, wn = (wave >> 1) << 6;
  const size_t bm = (size_t)blockIdx.y * 128, bn = (size_t)blockIdx.x * 128;

  f32x4 acc[4][4] = {};

  const __bf16* Abase = A + bm * K;
  const __bf16* Bbase = BT + bn * K;

  // staging chunk assignment: chunk c covers row=c>>2, k-part=(c&3)*8 (16B)
  const int c0 = wave * 64 + lane;
  const int c1 = c0 + 256;
  const size_t ga0 = (size_t)(c0 >> 2) * K + (size_t)(c0 & 3) * 8;
  const size_t ga1 = (size_t)(c1 >> 2) * K + (size_t)(c1 & 3) * 8;

  for (int k0 = 0; k0 < K; k0 += 32) {
    __builtin_amdgcn_global_load_lds(
      (const uint32_t __attribute__((address_space(1)))*)(Abase + ga0 + k0),
      (uint32_t __attribute__((address_space(3)))*)(As + wave*512), 16, 0, 0);
    __builtin_amdgcn_global_load_lds(
      (const uint32_t __attribute__((address_space(1)))*)(Abase + ga1 + k0),
      (uint32_t __attribute__((address_space(3)))*)(As + 2048 + wave*512), 16, 0, 0);
    __builtin_amdgcn_global_load_lds(
      (const uint32_t __attribute__((address_space(1)))*)(Bbase + ga0 + k0),
      (uint32_t __attribute__((address_space(3)))*)(Bs + wave*512), 16, 0, 0);
    __builtin_amdgcn_global_load_lds(
      (const uint32_t __attribute__((address_space(1)))*)(Bbase + ga1 + k0),
      (uint32_t __attribute__((address_space(3)))*)(Bs + 2048 + wave*512), 16, 0, 0);
    __syncthreads();
    bf16x8 af[4], bfr[4];
    #pragma unroll
    for (int i = 0; i < 4; i++)
      af[i] = *(const bf16x8*)(As + (wm + i*16 + l16)*32 + quad*8);
    #pragma unroll
    for (int j = 0; j < 4; j++)
      bfr[j] = *(const bf16x8*)(Bs + (wn + j*16 + l16)*32 + quad*8);
    #pragma unroll
    for (int i = 0; i < 4; i++)
      #pragma unroll
      for (int j = 0; j < 4; j++)
        acc[i][j] = __builtin_amdgcn_mfma_f32_16x16x32_bf16(af[i], bfr[j], acc[i][j], 0, 0, 0);
    __syncthreads();
  }

  // epilogue: C/D layout col=lane&15, row=quad*4+reg
  #pragma unroll
  for (int i = 0; i < 4; i++) {
    const int rowb = wm + i*16 + quad*4;
    #pragma unroll
    for (int r = 0; r < 4; r++) {
      const size_t gm = bm + rowb + r;
      if (gm >= (size_t)M) continue;
      const size_t rowoff = gm * (size_t)N + bn;
      #pragma unroll
      for (int j = 0; j < 4; j++) {
        const int cn = wn + j*16 + l16;
        float v = acc[i][j][r];
        if (bias)   v += bias[bn + cn];
        if (ADD)    v += addsrc[rowoff + cn];
        if (ACT == 1) v = 0.5f * v * (1.f + erff(v * 0.7071067811865475f));
        if (ACT == 2) v = fmaxf(v, 0.f);
        C[rowoff + cn] = (OT)v;
      }
    }
  }
}

// ---------------- fp32 GEMM (small head matmuls only) ----------------
template<int ACT>
__launch_bounds__(256)
__global__ void gemm_f32(const float* __restrict__ A, const float* __restrict__ B,
                         const float* __restrict__ bias, const float* __restrict__ addsrc,
                         float* __restrict__ C, int M, int N, int K)
{
  __shared__ float As[8][132];
  __shared__ float Bs[8][132];
  int tid = threadIdx.x;
  int tx = tid & 15, ty = tid >> 4;
  int bm = blockIdx.y * 128, bn = blockIdx.x * 128;
  float acc[8][8];
  #pragma unroll
  for (int i = 0; i < 8; i++)
    #pragma unroll
    for (int j = 0; j < 8; j++) acc[i][j] = 0.f;

  for (int k0 = 0; k0 < K; k0 += 8) {
    #pragma unroll
    for (int i = 0; i < 4; i++) {
      int idx = tid + i*256;
      int m = idx >> 3, k = idx & 7;
      int gm = bm + m, gk = k0 + k;
      As[k][m] = (gm < M && gk < K) ? A[(size_t)gm*K + gk] : 0.f;
      int kb = idx >> 7, nn = idx & 127;
      int gk2 = k0 + kb, gn = bn + nn;
      Bs[kb][nn] = (gk2 < K && gn < N) ? B[(size_t)gk2*N + gn] : 0.f;
    }
    __syncthreads();
    #pragma unroll
    for (int kk = 0; kk < 8; kk++) {
      float a[8], bb[8];
      #pragma unroll
      for (int i = 0; i < 8; i++) a[i] = As[kk][ty*8 + i];
      #pragma unroll
      for (int j = 0; j < 8; j++) bb[j] = Bs[kk][tx*8 + j];
      #pragma unroll
      for (int i = 0; i < 8; i++)
        #pragma unroll
        for (int j = 0; j < 8; j++) acc[i][j] += a[i] * bb[j];
    }
    __syncthreads();
  }

  #pragma unroll
  for (int i = 0; i < 8; i++) {
    int gm = bm + ty*8 + i;
    if (gm >= M) continue;
    #pragma unroll
    for (int j = 0; j < 8; j++) {
      int gn = bn + tx*8 + j;
      if (gn >= N) continue;
      float v = acc[i][j];
      if (bias)   v += bias[gn];
      if (addsrc) v += addsrc[(size_t)gm*N + gn];
      if (ACT == 1) v = 0.5f * v * (1.f + erff(v * 0.7071067811865475f));
      if (ACT == 2) v = fmaxf(v, 0.f);
      C[(size_t)gm*N + gn] = v;
    }
  }
}

// ---------------- Fused attention per (n, head), fp32 math, bf16 out ----------------
__launch_bounds__(1024)
__global__ void attn_kernel(const float* __restrict__ QKV, __bf16* __restrict__ O)
{
  __shared__ float Ks[STOK*65];
  __shared__ float Vs[STOK*65];
  __shared__ float Ps[16*200];
  int blk = blockIdx.x;
  int n = blk / NHEAD, h = blk % NHEAD;
  const float* base = QKV + (size_t)n*STOK*(3*DM) + (size_t)h*HDIM;
  int tid = threadIdx.x;
  for (int idx = tid; idx < STOK*HDIM; idx += 1024) {
    int j = idx >> 6, d = idx & 63;
    const float* row = base + (size_t)j*(3*DM);
    Ks[j*65 + d] = row[DM + d];
    Vs[j*65 + d] = row[2*DM + d];
  }
  __syncthreads();
  int w = tid >> 6, lane = tid & 63;
  for (int r = w; r < STOK; r += 16) {
    float qv = base[(size_t)r*(3*DM) + lane];
    float s0 = 0.f, s1 = 0.f, s2 = 0.f, s3 = 0.f;
    int j3 = 192 + lane;
    int j3c = (j3 < STOK) ? j3 : (STOK - 1);
    #pragma unroll 16
    for (int d = 0; d < 64; d++) {
      float qd = __shfl(qv, d, 64);
      s0 += qd * Ks[lane*65 + d];
      s1 += qd * Ks[(64 + lane)*65 + d];
      s2 += qd * Ks[(128 + lane)*65 + d];
      s3 += qd * Ks[j3c*65 + d];
    }
    const float scale = 0.125f;
    s0 *= scale; s1 *= scale; s2 *= scale; s3 *= scale;
    if (j3 >= STOK) s3 = -INFINITY;
    float mx = fmaxf(fmaxf(s0, s1), fmaxf(s2, s3));
    #pragma unroll
    for (int o = 32; o > 0; o >>= 1) mx = fmaxf(mx, __shfl_xor(mx, o, 64));
    float p0 = expf(s0 - mx), p1 = expf(s1 - mx), p2 = expf(s2 - mx);
    float p3 = (j3 < STOK) ? expf(s3 - mx) : 0.f;
    float sm = p0 + p1 + p2 + p3;
    #pragma unroll
    for (int o = 32; o > 0; o >>= 1) sm += __shfl_xor(sm, o, 64);
    float inv = 1.f / sm;
    float* pr = Ps + w*200;
    pr[lane] = p0*inv; pr[64 + lane] = p1*inv; pr[128 + lane] = p2*inv;
    if (j3 < STOK) pr[j3] = p3*inv;
    __builtin_amdgcn_wave_barrier();
    float oa = 0.f;
    #pragma unroll 4
    for (int j = 0; j < STOK; j++) oa += pr[j] * Vs[j*65 + lane];
    O[((size_t)n*STOK + r)*DM + (size_t)h*HDIM + lane] = (__bf16)oa;
    __builtin_amdgcn_wave_barrier();
  }
}

// ---------------- Host launch ----------------
extern "C" void kernel_launch(void* const* d_in, const int* in_sizes, int n_in,
                              void* d_out, int out_size, void* d_ws, size_t ws_size,
                              hipStream_t stream)
{
  (void)in_sizes; (void)n_in; (void)out_size; (void)ws_size;
  const float* x       = (const float*)d_in[0];
  const float* patch_w = (const float*)d_in[1];
  const float* patch_b = (const float*)d_in[2];
  const float* cls_tok = (const float*)d_in[3];
  const float* pos     = (const float*)d_in[4];
  const float* ln1_s   = (const float*)d_in[5];
  const float* ln1_b   = (const float*)d_in[6];
  const float* qkv_w   = (const float*)d_in[7];
  const float* qkv_b   = (const float*)d_in[8];
  const float* proj_w  = (const float*)d_in[9];
  const float* proj_b  = (const float*)d_in[10];
  const float* ln2_s   = (const float*)d_in[11];
  const float* ln2_b   = (const float*)d_in[12];
  const float* mlp1_w  = (const float*)d_in[13];
  const float* mlp1_b  = (const float*)d_in[14];
  const float* mlp2_w  = (const float*)d_in[15];
  const float* mlp2_b  = (const float*)d_in[16];
  const float* lnf_s   = (const float*)d_in[17];
  const float* lnf_b   = (const float*)d_in[18];
  const float* head_w  = (const float*)d_in[19];
  const float* head_b  = (const float*)d_in[20];
  const float* fc1_w   = (const float*)d_in[21];
  const float* fc1_b   = (const float*)d_in[22];
  const float* fc2_w   = (const float*)d_in[23];
  const float* fc2_b   = (const float*)d_in[24];
  float* out = (float*)d_out;

  const int ROWS = NB * STOK;            // 6304, padded to 6400 for MFMA staging
  char* base = (char*)d_ws;
  float*  tok  = (float*)base;                       // 6304*768*4      = 19,365,888
  __bf16* H    = (__bf16*)(base + 19365888);         // 6400*768*2      =  9,830,400
  char*   arena = base + 29196288;                   // 58,097,664 arena
  float*  QKV  = (float*)arena;                      // 6304*2304*4
  __bf16* Mb   = (__bf16*)arena;                     // 6400*3072*2 (alias)
  float*  img  = (float*)arena;                      // 32*3*225*225*4 (alias)
  float*  Ctmp = (float*)arena;                      // 6272*768*4 (alias, after img dead)
  char*   wb   = base + 87293952;
  __bf16* wqkvT  = (__bf16*)wb;                      // 2304*768*2 = 3,538,944
  __bf16* wprojT = (__bf16*)(wb + 3538944);          //  768*768*2 = 1,179,648
  __bf16* wmlp1T = (__bf16*)(wb + 4718592);          // 3072*768*2 = 4,718,592
  __bf16* wmlp2T = (__bf16*)(wb + 9437184);          //  768*3072*2= 4,718,592
  __bf16* pwT    = (__bf16*)(wb + 14155776);         //  768*768*2 = 1,179,648
  char*   sm   = wb + 15335424;                      // small buffers
  int*    ids  = (int*)sm;
  int*    offs = (int*)(sm + 4096);
  int*    jitv = (int*)(sm + 8192);
  float*  clsb = (float*)(sm + 16384);               // 32*768*4
  float*  feat = (float*)(sm + 16384 + 98304);       // 32*1000*4
  float*  f1   = feat + 32*NCLSD;                    // 32*1000*4

  dim3 blkT(32, 8);

  // 1. RNG + target
  rng_kernel<<<1, 1024, 0, stream>>>(ids, offs, jitv, out + NB*NFR*2);
  // 2. augmentation -> img
  augment_kernel<<<NB*NFR*3, 256, 0, stream>>>(x, ids, offs, jitv, img);
  // 3. patchify -> Xp (bf16, in H)
  gather_patches<<<NB*196, 256, 0, stream>>>(img, H);
  // 4. patch embed (bf16 MFMA)
  convT<<<dim3(DM/32, DM/32), blkT, 0, stream>>>(patch_w, pwT, DM, DM);
  gemm_bf16<0,false,float><<<dim3(DM/128, 49), 256, 0, stream>>>(
      H, pwT, nullptr, nullptr, Ctmp, NB*196, DM, DM);
  // 5. assemble tokens (+cls, +pos, +bias)
  assemble_tok<<<ROWS, 256, 0, stream>>>(Ctmp, patch_b, cls_tok, pos, tok);

  // 6. transformer layers
  for (int l = 0; l < NLAYER; l++) {
    convT<<<dim3(3*DM/32, DM/32), blkT, 0, stream>>>(qkv_w + (size_t)l*DM*3*DM, wqkvT, DM, 3*DM);
    convT<<<dim3(DM/32, DM/32),   blkT, 0, stream>>>(proj_w + (size_t)l*DM*DM,  wprojT, DM, DM);
    convT<<<dim3(MLPD/32, DM/32), blkT, 0, stream>>>(mlp1_w + (size_t)l*DM*MLPD, wmlp1T, DM, MLPD);
    convT<<<dim3(DM/32, MLPD/32), blkT, 0, stream>>>(mlp2_w + (size_t)l*MLPD*DM, wmlp2T, MLPD, DM);

    ln_kernel<__bf16><<<ROWS, 256, 0, stream>>>(tok, DM, H, ln1_s + (size_t)l*DM, ln1_b + (size_t)l*DM);
    gemm_bf16<0,false,float><<<dim3(3*DM/128, 50), 256, 0, stream>>>(
        H, wqkvT, qkv_b + (size_t)l*3*DM, nullptr, QKV, ROWS, 3*DM, DM);
    attn_kernel<<<NB*NHEAD, 1024, 0, stream>>>(QKV, H);
    gemm_bf16<0,true,float><<<dim3(DM/128, 50), 256, 0, stream>>>(
        H, wprojT, proj_b + (size_t)l*DM, tok, tok, ROWS, DM, DM);
    ln_kernel<__bf16><<<ROWS, 256, 0, stream>>>(tok, DM, H, ln2_s + (size_t)l*DM, ln2_b + (size_t)l*DM);
    gemm_bf16<1,false,__bf16><<<dim3(MLPD/128, 50), 256, 0, stream>>>(
        H, wmlp1T, mlp1_b + (size_t)l*MLPD, nullptr, Mb, ROWS, MLPD, DM);
    gemm_bf16<0,true,float><<<dim3(DM/128, 50), 256, 0, stream>>>(
        Mb, wmlp2T, mlp2_b + (size_t)l*DM, tok, tok, ROWS, DM, MLPD);
  }

  // 7. final LN on cls rows (fp32 out)
  ln_kernel<float><<<NB, 256, 0, stream>>>(tok, (size_t)STOK*DM, clsb, lnf_s, lnf_b);
  // 8. head (small fp32 GEMMs)
  {
    dim3 g((NCLSD + 127)/128, 1);
    gemm_f32<0><<<g, 256, 0, stream>>>(clsb, head_w, head_b, nullptr, feat, NB, NCLSD, DM);
    gemm_f32<2><<<g, 256, 0, stream>>>(feat, fc1_w, fc1_b, nullptr, f1, NB, NCLSD, NCLSD);
    gemm_f32<0><<<dim3(1,1), 256, 0, stream>>>(f1, fc2_w, fc2_b, nullptr, out, NB, 2*NFR, NCLSD);
  }
}

// Round 3
// 5926.652 us; speedup vs baseline: 6.6803x; 1.6318x over previous
//
#include <hip/hip_runtime.h>
#include <stdint.h>

#define NB 32          // batch
#define NFR 9          // fragments
#define PF 75          // fragment size
#define PUZS 225
#define DM 768
#define STOK 197
#define NHEAD 12
#define HDIM 64
#define MLPD 3072
#define NLAYER 12
#define NCLSD 1000

typedef __bf16 bf16x8 __attribute__((ext_vector_type(8)));
typedef float f32x4 __attribute__((ext_vector_type(4)));

// ---------------- Threefry-2x32 (JAX-compatible, 20 rounds) ----------------
__device__ __forceinline__ uint32_t rotl32(uint32_t v, int d){ return (v<<d)|(v>>(32-d)); }

__device__ __forceinline__ void tf2x32(uint32_t k0, uint32_t k1, uint32_t x0, uint32_t x1,
                                       uint32_t& o0, uint32_t& o1)
{
  uint32_t ks2 = k0 ^ k1 ^ 0x1BD11BDAu;
  x0 += k0; x1 += k1;
#define TFR(r) { x0 += x1; x1 = rotl32(x1,(r)); x1 ^= x0; }
  TFR(13) TFR(15) TFR(26) TFR(6)
  x0 += k1;  x1 += ks2 + 1u;
  TFR(17) TFR(29) TFR(16) TFR(24)
  x0 += ks2; x1 += k0 + 2u;
  TFR(13) TFR(15) TFR(26) TFR(6)
  x0 += k0;  x1 += k1 + 3u;
  TFR(17) TFR(29) TFR(16) TFR(24)
  x0 += k1;  x1 += ks2 + 4u;
  TFR(13) TFR(15) TFR(26) TFR(6)
  x0 += ks2; x1 += k0 + 5u;
#undef TFR
  o0 = x0; o1 = x1;
}

__device__ __forceinline__ uint32_t tf_bits(uint32_t k0, uint32_t k1, uint32_t idx)
{
  uint32_t a, b; tf2x32(k0, k1, 0u, idx, a, b); return a ^ b;
}

// ---------------- RNG setup: noise->argsort, crop offsets, jitter, target ----------------
__global__ void rng_kernel(int* __restrict__ ids_shuffle, int* __restrict__ offs,
                           int* __restrict__ jitv, float* __restrict__ target_out)
{
  __shared__ float noise[NB*NFR];
  int t = threadIdx.x;
  uint32_t kn0,kn1,kc0,kc1,kj0,kj1;
  tf2x32(0u,42u,0u,0u,kn0,kn1);
  tf2x32(0u,42u,0u,1u,kc0,kc1);
  tf2x32(0u,42u,0u,2u,kj0,kj1);

  if (t < NB*NFR) {
    uint32_t bits = tf_bits(kn0, kn1, (uint32_t)t);
    noise[t] = __uint_as_float((bits >> 9) | 0x3f800000u) - 1.0f;
  }
  if (t < NB*NFR*2) {
    uint32_t c10,c11,c20,c21;
    tf2x32(kc0,kc1,0u,0u,c10,c11);
    tf2x32(kc0,kc1,0u,1u,c20,c21);
    uint32_t hb = tf_bits(c10,c11,(uint32_t)t);
    uint32_t lb = tf_bits(c20,c21,(uint32_t)t);
    offs[t] = (int)((((hb % 12u) * 4u) + (lb % 12u)) % 12u);
  }
  if (t < NB*NFR*3) {
    uint32_t c10,c11,c20,c21;
    tf2x32(kj0,kj1,0u,0u,c10,c11);
    tf2x32(kj0,kj1,0u,1u,c20,c21);
    uint32_t hb = tf_bits(c10,c11,(uint32_t)t);
    uint32_t lb = tf_bits(c20,c21,(uint32_t)t);
    jitv[t] = -2 + (int)(((hb % 5u) + (lb % 5u)) % 5u);
  }
  __syncthreads();
  if (t < NB) {
    float v[NFR]; int idx[NFR];
    for (int i = 0; i < NFR; i++) { v[i] = noise[t*NFR + i]; idx[i] = i; }
    for (int i = 1; i < NFR; i++) {
      float kv = v[i]; int ki = idx[i]; int j = i - 1;
      while (j >= 0 && v[j] > kv) { v[j+1] = v[j]; idx[j+1] = idx[j]; j--; }
      v[j+1] = kv; idx[j+1] = ki;
    }
    int restore[NFR];
    for (int k = 0; k < NFR; k++) { ids_shuffle[t*NFR + k] = idx[k]; restore[idx[k]] = k; }
    for (int f = 0; f < NFR; f++) {
      int r = restore[f];
      target_out[(t*NFR + f)*2 + 0] = (float)(r / 3);
      target_out[(t*NFR + f)*2 + 1] = (float)(r % 3);
    }
  }
}

// ---------------- Augment ----------------
__launch_bounds__(256)
__global__ void augment_kernel(const float* __restrict__ x, const int* __restrict__ ids_shuffle,
                               const int* __restrict__ offs, const int* __restrict__ jitv,
                               float* __restrict__ img)
{
  int bid = blockIdx.x;          // m*3 + c
  int m = bid / 3, c = bid % 3;
  int n = m / NFR, k = m % NFR;
  int fs = ids_shuffle[m];
  int si = fs / 3, sj = fs % 3;
  int gi = k / 3,  gj = k % 3;
  int oy = offs[2*m], ox = offs[2*m+1];
  float jv = (float)jitv[3*m + c];
  const float* src = x + (((size_t)n*3 + c)*PUZS + (size_t)si*PF)*PUZS + (size_t)sj*PF;

  __shared__ float vals[PF*PF];
  __shared__ double dred[256];
  int tid = threadIdx.x;
  const float sc = 64.0f / 75.0f;

  double lsum = 0.0;
  for (int p = tid; p < PF*PF; p += 256) {
    int py = p / PF, px = p % PF;
    float yy = (py + 0.5f)*sc - 0.5f;
    float xx = (px + 0.5f)*sc - 0.5f;
    int y0 = (int)floorf(yy); float fy = yy - (float)y0;
    int x0 = (int)floorf(xx); float fx = xx - (float)x0;
    int y0c = min(max(y0, 0), 63), y1c = min(max(y0+1, 0), 63);
    int x0c = min(max(x0, 0), 63), x1c = min(max(x0+1, 0), 63);
    const float* r0 = src + (size_t)(oy + y0c)*PUZS + ox;
    const float* r1 = src + (size_t)(oy + y1c)*PUZS + ox;
    float v00 = r0[x0c], v01 = r0[x1c], v10 = r1[x0c], v11 = r1[x1c];
    float v = (1.f-fy)*((1.f-fx)*v00 + fx*v01) + fy*((1.f-fx)*v10 + fx*v11);
    v = fminf(fmaxf(v + jv, 0.f), 255.f);
    vals[p] = v;
    lsum += (double)v;
  }
  dred[tid] = lsum; __syncthreads();
  for (int s = 128; s > 0; s >>= 1) { if (tid < s) dred[tid] += dred[tid+s]; __syncthreads(); }
  double mean = dred[0] / (double)(PF*PF);
  __syncthreads();
  double lss = 0.0;
  for (int p = tid; p < PF*PF; p += 256) { double d = (double)vals[p] - mean; lss += d*d; }
  dred[tid] = lss; __syncthreads();
  for (int s = 128; s > 0; s >>= 1) { if (tid < s) dred[tid] += dred[tid+s]; __syncthreads(); }
  double var = dred[0] / (double)(PF*PF - 1);
  float sdev = (float)sqrt(var);
  if (sdev == 0.f) sdev = 1.f;
  float mf = (float)mean;
  float* dst = img + (((size_t)n*3 + c)*PUZS + (size_t)gi*PF)*PUZS + (size_t)gj*PF;
  for (int p = tid; p < PF*PF; p += 256)
    dst[(size_t)(p/PF)*PUZS + (p%PF)] = (vals[p] - mf) / sdev;
}

// ---------------- Patch gather (fp32 img -> bf16 Xp) ----------------
__global__ void gather_patches(const float* __restrict__ img, __bf16* __restrict__ Xp)
{
  int tg = blockIdx.x;           // n*196 + t
  int n = tg / 196, t = tg % 196;
  int ti = t / 14, tj = t % 14;
  for (int d = threadIdx.x; d < DM; d += 256) {
    int c = d >> 8, r = (d >> 4) & 15, col = d & 15;
    Xp[(size_t)tg*DM + d] = (__bf16)
      img[(((size_t)n*3 + c)*PUZS + (size_t)(ti*16 + r))*PUZS + (tj*16 + col)];
  }
}

__global__ void assemble_tok(const float* __restrict__ Ctmp, const float* __restrict__ patch_b,
                             const float* __restrict__ cls_tok, const float* __restrict__ pos,
                             float* __restrict__ tok)
{
  int row = blockIdx.x;          // n*197 + t
  int n = row / STOK, t = row % STOK;
  float* o = tok + (size_t)row*DM;
  if (t == 0) {
    for (int i = threadIdx.x; i < DM; i += 256) o[i] = cls_tok[i] + pos[i];
  } else {
    const float* cm = Ctmp + ((size_t)n*196 + (t-1))*DM;
    const float* pp = pos + (size_t)t*DM;
    for (int i = threadIdx.x; i < DM; i += 256) o[i] = cm[i] + patch_b[i] + pp[i];
  }
}

// ---------------- LayerNorm (templated output dtype) ----------------
template<typename OT>
__launch_bounds__(256)
__global__ void ln_kernel(const float* __restrict__ X, size_t xstride, OT* __restrict__ Y,
                          const float* __restrict__ g, const float* __restrict__ b)
{
  __shared__ float buf[DM];
  __shared__ float red[256];
  int r = blockIdx.x, tid = threadIdx.x;
  const float* xr = X + (size_t)r * xstride;
  float lsum = 0.f;
  for (int i = tid; i < DM; i += 256) { float v = xr[i]; buf[i] = v; lsum += v; }
  red[tid] = lsum; __syncthreads();
  for (int s = 128; s > 0; s >>= 1) { if (tid < s) red[tid] += red[tid+s]; __syncthreads(); }
  float mean = red[0] / (float)DM;
  __syncthreads();
  float lss = 0.f;
  for (int i = tid; i < DM; i += 256) { float d = buf[i] - mean; lss += d*d; }
  red[tid] = lss; __syncthreads();
  for (int s = 128; s > 0; s >>= 1) { if (tid < s) red[tid] += red[tid+s]; __syncthreads(); }
  float rstd = rsqrtf(red[0] / (float)DM + 1e-6f);
  OT* yr = Y + (size_t)r * DM;
  for (int i = tid; i < DM; i += 256) yr[i] = (OT)((buf[i] - mean) * rstd * g[i] + b[i]);
}

// ---------------- Transpose+convert: fp32 [K][N] -> bf16 [N][K] ----------------
__launch_bounds__(256)
__global__ void convT(const float* __restrict__ src, __bf16* __restrict__ dst, int K, int N)
{
  __shared__ float t[32][33];
  int k0 = blockIdx.y*32, n0 = blockIdx.x*32;
  int tx = threadIdx.x, ty = threadIdx.y; // 32x8
  #pragma unroll
  for (int i = 0; i < 32; i += 8)
    t[ty+i][tx] = src[(size_t)(k0+ty+i)*N + n0+tx];
  __syncthreads();
  #pragma unroll
  for (int i = 0; i < 32; i += 8)
    dst[(size_t)(n0+ty+i)*K + k0+tx] = (__bf16)t[tx][ty+i];
}

// ---------------- bf16 MFMA GEMM: C = act(A @ BT^T + bias [+ addsrc]) ----------------
template<int ACT, bool ADD, typename OT>
__launch_bounds__(256)
__global__ void gemm_bf16(const __bf16* __restrict__ A, const __bf16* __restrict__ BT,
                          const float* __restrict__ bias, const float* __restrict__ addsrc,
                          OT* __restrict__ C, int M, int N, int K)
{
  __shared__ __attribute__((aligned(16))) __bf16 As[128*32];
  __shared__ __attribute__((aligned(16))) __bf16 Bs[128*32];
  const int tid = threadIdx.x;
  const int wave = tid >> 6, lane = tid & 63;
  const int quad = lane >> 4, l16 = lane & 15;
  const int wm = (wave & 1) << 6, wn = (wave >> 1) << 6;
  const size_t bm = (size_t)blockIdx.y * 128, bn = (size_t)blockIdx.x * 128;

  f32x4 acc[4][4] = {};

  const __bf16* Abase = A + bm * K;
  const __bf16* Bbase = BT + bn * K;

  const int c0 = wave * 64 + lane;
  const int c1 = c0 + 256;
  const size_t ga0 = (size_t)(c0 >> 2) * K + (size_t)(c0 & 3) * 8;
  const size_t ga1 = (size_t)(c1 >> 2) * K + (size_t)(c1 & 3) * 8;

  for (int k0 = 0; k0 < K; k0 += 32) {
    __builtin_amdgcn_global_load_lds(
      (const uint32_t __attribute__((address_space(1)))*)(Abase + ga0 + k0),
      (uint32_t __attribute__((address_space(3)))*)(As + wave*512), 16, 0, 0);
    __builtin_amdgcn_global_load_lds(
      (const uint32_t __attribute__((address_space(1)))*)(Abase + ga1 + k0),
      (uint32_t __attribute__((address_space(3)))*)(As + 2048 + wave*512), 16, 0, 0);
    __builtin_amdgcn_global_load_lds(
      (const uint32_t __attribute__((address_space(1)))*)(Bbase + ga0 + k0),
      (uint32_t __attribute__((address_space(3)))*)(Bs + wave*512), 16, 0, 0);
    __builtin_amdgcn_global_load_lds(
      (const uint32_t __attribute__((address_space(1)))*)(Bbase + ga1 + k0),
      (uint32_t __attribute__((address_space(3)))*)(Bs + 2048 + wave*512), 16, 0, 0);
    __syncthreads();
    bf16x8 af[4], bfr[4];
    #pragma unroll
    for (int i = 0; i < 4; i++)
      af[i] = *(const bf16x8*)(As + (wm + i*16 + l16)*32 + quad*8);
    #pragma unroll
    for (int j = 0; j < 4; j++)
      bfr[j] = *(const bf16x8*)(Bs + (wn + j*16 + l16)*32 + quad*8);
    #pragma unroll
    for (int i = 0; i < 4; i++)
      #pragma unroll
      for (int j = 0; j < 4; j++)
        acc[i][j] = __builtin_amdgcn_mfma_f32_16x16x32_bf16(af[i], bfr[j], acc[i][j], 0, 0, 0);
    __syncthreads();
  }

  #pragma unroll
  for (int i = 0; i < 4; i++) {
    const int rowb = wm + i*16 + quad*4;
    #pragma unroll
    for (int r = 0; r < 4; r++) {
      const size_t gm = bm + rowb + r;
      if (gm >= (size_t)M) continue;
      const size_t rowoff = gm * (size_t)N + bn;
      #pragma unroll
      for (int j = 0; j < 4; j++) {
        const int cn = wn + j*16 + l16;
        float v = acc[i][j][r];
        if (bias)   v += bias[bn + cn];
        if (ADD)    v += addsrc[rowoff + cn];
        if (ACT == 1) v = 0.5f * v * (1.f + erff(v * 0.7071067811865475f));
        if (ACT == 2) v = fmaxf(v, 0.f);
        C[rowoff + cn] = (OT)v;
      }
    }
  }
}

// ---------------- fp32 GEMM (small head matmuls only) ----------------
template<int ACT>
__launch_bounds__(256)
__global__ void gemm_f32(const float* __restrict__ A, const float* __restrict__ B,
                         const float* __restrict__ bias, const float* __restrict__ addsrc,
                         float* __restrict__ C, int M, int N, int K)
{
  __shared__ float As[8][132];
  __shared__ float Bs[8][132];
  int tid = threadIdx.x;
  int tx = tid & 15, ty = tid >> 4;
  int bm = blockIdx.y * 128, bn = blockIdx.x * 128;
  float acc[8][8];
  #pragma unroll
  for (int i = 0; i < 8; i++)
    #pragma unroll
    for (int j = 0; j < 8; j++) acc[i][j] = 0.f;

  for (int k0 = 0; k0 < K; k0 += 8) {
    #pragma unroll
    for (int i = 0; i < 4; i++) {
      int idx = tid + i*256;
      int m = idx >> 3, k = idx & 7;
      int gm = bm + m, gk = k0 + k;
      As[k][m] = (gm < M && gk < K) ? A[(size_t)gm*K + gk] : 0.f;
      int kb = idx >> 7, nn = idx & 127;
      int gk2 = k0 + kb, gn = bn + nn;
      Bs[kb][nn] = (gk2 < K && gn < N) ? B[(size_t)gk2*N + gn] : 0.f;
    }
    __syncthreads();
    #pragma unroll
    for (int kk = 0; kk < 8; kk++) {
      float a[8], bb[8];
      #pragma unroll
      for (int i = 0; i < 8; i++) a[i] = As[kk][ty*8 + i];
      #pragma unroll
      for (int j = 0; j < 8; j++) bb[j] = Bs[kk][tx*8 + j];
      #pragma unroll
      for (int i = 0; i < 8; i++)
        #pragma unroll
        for (int j = 0; j < 8; j++) acc[i][j] += a[i] * bb[j];
    }
    __syncthreads();
  }

  #pragma unroll
  for (int i = 0; i < 8; i++) {
    int gm = bm + ty*8 + i;
    if (gm >= M) continue;
    #pragma unroll
    for (int j = 0; j < 8; j++) {
      int gn = bn + tx*8 + j;
      if (gn >= N) continue;
      float v = acc[i][j];
      if (bias)   v += bias[gn];
      if (addsrc) v += addsrc[(size_t)gm*N + gn];
      if (ACT == 1) v = 0.5f * v * (1.f + erff(v * 0.7071067811865475f));
      if (ACT == 2) v = fmaxf(v, 0.f);
      C[(size_t)gm*N + gn] = v;
    }
  }
}

// ---------------- MFMA attention: block = (n, head, m-half) ----------------
// QKVb: bf16 [ROWS(+pad)][2304] (q|k|v each 768 = 12 heads x 64)
// O: bf16 [ROWS][768]
__launch_bounds__(256)
__global__ void attn_mfma(const __bf16* __restrict__ QKVb, __bf16* __restrict__ O)
{
  __shared__ __attribute__((aligned(16))) __bf16 Ks[208*72];     // [key_row][k] stride 72
  __shared__ __attribute__((aligned(16))) __bf16 Vt[64*232];     // [d][key_col] stride 232
  __shared__ __attribute__((aligned(16))) __bf16 Ps[4][16*232];  // per-wave P, stride 232

  const int bid = blockIdx.x;
  const int n = bid / 24, rem = bid % 24, h = rem >> 1, half = rem & 1;
  const int tid = threadIdx.x, wave = tid >> 6, lane = tid & 63;
  const int quad = lane >> 4, l16 = lane & 15;
  const __bf16* qb = QKVb + (size_t)n*STOK*2304 + h*64;
  const __bf16* kb = qb + DM;
  const __bf16* vb = qb + 2*DM;

  // zero Ks rows 197..207 (11 rows * 72 el = 792 el = 396 words)
  for (int i = tid; i < 396; i += 256) ((uint32_t*)(Ks + 197*72))[i] = 0u;
  // zero Vt cols 196..231 (64 rows * 36 el = 18 words/row)
  for (int i = tid; i < 64*18; i += 256) {
    int d = i / 18, w = i % 18;
    ((uint32_t*)(Vt + d*232 + 196))[w] = 0u;
  }
  // zero Ps cols 208..223 for all 4 waves (read-covered, never written by softmax)
  for (int i = tid; i < 512; i += 256) {
    int w = i >> 7, r = (i >> 3) & 15, c = i & 7;
    ((uint32_t*)(Ps[w] + r*232 + 208))[c] = 0u;
  }
  // stage K rows 0..196 (vector 16B)
  for (int idx = tid; idx < 197*8; idx += 256) {
    int r = idx >> 3, c8 = (idx & 7) * 8;
    *(bf16x8*)(Ks + r*72 + c8) = *(const bf16x8*)(kb + (size_t)r*2304 + c8);
  }
  // stage V transposed
  for (int idx = tid; idx < 197*64; idx += 256) {
    int j = idx >> 6, d = idx & 63;
    Vt[d*232 + j] = vb[(size_t)j*2304 + d];
  }
  __syncthreads();

  const int t0 = half * 7;
  const int tcnt = half ? 6 : 7;
  __bf16* Pw = Ps[wave];

  for (int it = wave; it < tcnt; it += 4) {
    const int mt = t0 + it;
    // ---- S = Q K^T ----
    f32x4 s[13];
    #pragma unroll
    for (int t = 0; t < 13; t++) s[t] = (f32x4){0.f,0.f,0.f,0.f};
    #pragma unroll
    for (int ks = 0; ks < 2; ks++) {
      bf16x8 aq = *(const bf16x8*)(qb + (size_t)(mt*16 + l16)*2304 + ks*32 + quad*8);
      #pragma unroll
      for (int t = 0; t < 13; t++) {
        bf16x8 bk = *(const bf16x8*)(Ks + (t*16 + l16)*72 + ks*32 + quad*8);
        s[t] = __builtin_amdgcn_mfma_f32_16x16x32_bf16(aq, bk, s[t], 0, 0, 0);
      }
    }
    // ---- softmax (rows = quad*4 + r), fp32 ----
    const float scale = 0.125f;
    float mx[4] = {-INFINITY,-INFINITY,-INFINITY,-INFINITY};
    #pragma unroll
    for (int t = 0; t < 13; t++) {
      bool valid = (t*16 + l16) < STOK;
      #pragma unroll
      for (int r = 0; r < 4; r++) {
        float v = valid ? s[t][r] * scale : -INFINITY;
        s[t][r] = v;
        mx[r] = fmaxf(mx[r], v);
      }
    }
    #pragma unroll
    for (int r = 0; r < 4; r++)
      #pragma unroll
      for (int o = 1; o < 16; o <<= 1) mx[r] = fmaxf(mx[r], __shfl_xor(mx[r], o, 64));
    float sum[4] = {0.f,0.f,0.f,0.f};
    #pragma unroll
    for (int t = 0; t < 13; t++)
      #pragma unroll
      for (int r = 0; r < 4; r++) {
        float p = __expf(s[t][r] - mx[r]);
        s[t][r] = p; sum[r] += p;
      }
    #pragma unroll
    for (int r = 0; r < 4; r++)
      #pragma unroll
      for (int o = 1; o < 16; o <<= 1) sum[r] += __shfl_xor(sum[r], o, 64);
    // write P (bf16) to per-wave LDS in A-operand-friendly row-major [m][j]
    #pragma unroll
    for (int r = 0; r < 4; r++) {
      float inv = 1.f / sum[r];
      int row = quad*4 + r;
      #pragma unroll
      for (int t = 0; t < 13; t++)
        Pw[row*232 + t*16 + l16] = (__bf16)(s[t][r] * inv);
    }
    __builtin_amdgcn_wave_barrier();
    // ---- O = P V ----
    f32x4 o4[4];
    #pragma unroll
    for (int dt = 0; dt < 4; dt++) o4[dt] = (f32x4){0.f,0.f,0.f,0.f};
    #pragma unroll
    for (int ks = 0; ks < 7; ks++) {
      bf16x8 ap = *(const bf16x8*)(Pw + l16*232 + ks*32 + quad*8);
      #pragma unroll
      for (int dt = 0; dt < 4; dt++) {
        bf16x8 bv = *(const bf16x8*)(Vt + (dt*16 + l16)*232 + ks*32 + quad*8);
        o4[dt] = __builtin_amdgcn_mfma_f32_16x16x32_bf16(ap, bv, o4[dt], 0, 0, 0);
      }
    }
    #pragma unroll
    for (int r = 0; r < 4; r++) {
      int m = mt*16 + quad*4 + r;
      if (m < STOK) {
        size_t off = ((size_t)n*STOK + m)*DM + (size_t)h*HDIM;
        #pragma unroll
        for (int dt = 0; dt < 4; dt++)
          O[off + dt*16 + l16] = (__bf16)o4[dt][r];
      }
    }
    __builtin_amdgcn_wave_barrier();
  }
}

// ---------------- Host launch ----------------
extern "C" void kernel_launch(void* const* d_in, const int* in_sizes, int n_in,
                              void* d_out, int out_size, void* d_ws, size_t ws_size,
                              hipStream_t stream)
{
  (void)in_sizes; (void)n_in; (void)out_size; (void)ws_size;
  const float* x       = (const float*)d_in[0];
  const float* patch_w = (const float*)d_in[1];
  const float* patch_b = (const float*)d_in[2];
  const float* cls_tok = (const float*)d_in[3];
  const float* pos     = (const float*)d_in[4];
  const float* ln1_s   = (const float*)d_in[5];
  const float* ln1_b   = (const float*)d_in[6];
  const float* qkv_w   = (const float*)d_in[7];
  const float* qkv_b   = (const float*)d_in[8];
  const float* proj_w  = (const float*)d_in[9];
  const float* proj_b  = (const float*)d_in[10];
  const float* ln2_s   = (const float*)d_in[11];
  const float* ln2_b   = (const float*)d_in[12];
  const float* mlp1_w  = (const float*)d_in[13];
  const float* mlp1_b  = (const float*)d_in[14];
  const float* mlp2_w  = (const float*)d_in[15];
  const float* mlp2_b  = (const float*)d_in[16];
  const float* lnf_s   = (const float*)d_in[17];
  const float* lnf_b   = (const float*)d_in[18];
  const float* head_w  = (const float*)d_in[19];
  const float* head_b  = (const float*)d_in[20];
  const float* fc1_w   = (const float*)d_in[21];
  const float* fc1_b   = (const float*)d_in[22];
  const float* fc2_w   = (const float*)d_in[23];
  const float* fc2_b   = (const float*)d_in[24];
  float* out = (float*)d_out;

  const int ROWS = NB * STOK;            // 6304
  char* base = (char*)d_ws;
  float*  tok  = (float*)base;                       // 6304*768*4      = 19,365,888
  __bf16* H    = (__bf16*)(base + 19365888);         // 6400*768*2      =  9,830,400
  char*   arena = base + 29196288;                   // 58,097,664 arena
  __bf16* QKVb = (__bf16*)arena;                     // 6400*2304*2 = 29,491,200 (alias)
  __bf16* Mb   = (__bf16*)arena;                     // 6400*3072*2 (alias)
  float*  img  = (float*)arena;                      // 32*3*225*225*4 (alias)
  float*  Ctmp = (float*)arena;                      // 6272*768*4 (alias, img dead)
  char*   wb   = base + 87293952;
  __bf16* wqkvT  = (__bf16*)wb;                      // 2304*768*2 = 3,538,944
  __bf16* wprojT = (__bf16*)(wb + 3538944);          //  768*768*2 = 1,179,648
  __bf16* wmlp1T = (__bf16*)(wb + 4718592);          // 3072*768*2 = 4,718,592
  __bf16* wmlp2T = (__bf16*)(wb + 9437184);          //  768*3072*2= 4,718,592
  __bf16* pwT    = (__bf16*)(wb + 14155776);         //  768*768*2 = 1,179,648
  char*   sm   = wb + 15335424;
  int*    ids  = (int*)sm;
  int*    offs = (int*)(sm + 4096);
  int*    jitv = (int*)(sm + 8192);
  float*  clsb = (float*)(sm + 16384);               // 32*768*4
  float*  feat = (float*)(sm + 16384 + 98304);       // 32*1000*4
  float*  f1   = feat + 32*NCLSD;                    // 32*1000*4

  dim3 blkT(32, 8);

  // 1. RNG + target
  rng_kernel<<<1, 1024, 0, stream>>>(ids, offs, jitv, out + NB*NFR*2);
  // 2. augmentation -> img
  augment_kernel<<<NB*NFR*3, 256, 0, stream>>>(x, ids, offs, jitv, img);
  // 3. patchify -> Xp (bf16, in H)
  gather_patches<<<NB*196, 256, 0, stream>>>(img, H);
  // 4. patch embed (bf16 MFMA)
  convT<<<dim3(DM/32, DM/32), blkT, 0, stream>>>(patch_w, pwT, DM, DM);
  gemm_bf16<0,false,float><<<dim3(DM/128, 49), 256, 0, stream>>>(
      H, pwT, nullptr, nullptr, Ctmp, NB*196, DM, DM);
  // 5. assemble tokens (+cls, +pos, +bias)
  assemble_tok<<<ROWS, 256, 0, stream>>>(Ctmp, patch_b, cls_tok, pos, tok);

  // 6. transformer layers
  for (int l = 0; l < NLAYER; l++) {
    convT<<<dim3(3*DM/32, DM/32), blkT, 0, stream>>>(qkv_w + (size_t)l*DM*3*DM, wqkvT, DM, 3*DM);
    convT<<<dim3(DM/32, DM/32),   blkT, 0, stream>>>(proj_w + (size_t)l*DM*DM,  wprojT, DM, DM);
    convT<<<dim3(MLPD/32, DM/32), blkT, 0, stream>>>(mlp1_w + (size_t)l*DM*MLPD, wmlp1T, DM, MLPD);
    convT<<<dim3(DM/32, MLPD/32), blkT, 0, stream>>>(mlp2_w + (size_t)l*MLPD*DM, wmlp2T, MLPD, DM);

    ln_kernel<__bf16><<<ROWS, 256, 0, stream>>>(tok, DM, H, ln1_s + (size_t)l*DM, ln1_b + (size_t)l*DM);
    gemm_bf16<0,false,__bf16><<<dim3(3*DM/128, 50), 256, 0, stream>>>(
        H, wqkvT, qkv_b + (size_t)l*3*DM, nullptr, QKVb, ROWS, 3*DM, DM);
    attn_mfma<<<NB*NHEAD*2, 256, 0, stream>>>(QKVb, H);
    gemm_bf16<0,true,float><<<dim3(DM/128, 50), 256, 0, stream>>>(
        H, wprojT, proj_b + (size_t)l*DM, tok, tok, ROWS, DM, DM);
    ln_kernel<__bf16><<<ROWS, 256, 0, stream>>>(tok, DM, H, ln2_s + (size_t)l*DM, ln2_b + (size_t)l*DM);
    gemm_bf16<1,false,__bf16><<<dim3(MLPD/128, 50), 256, 0, stream>>>(
        H, wmlp1T, mlp1_b + (size_t)l*MLPD, nullptr, Mb, ROWS, MLPD, DM);
    gemm_bf16<0,true,float><<<dim3(DM/128, 50), 256, 0, stream>>>(
        Mb, wmlp2T, mlp2_b + (size_t)l*DM, tok, tok, ROWS, DM, MLPD);
  }

  // 7. final LN on cls rows (fp32 out)
  ln_kernel<float><<<NB, 256, 0, stream>>>(tok, (size_t)STOK*DM, clsb, lnf_s, lnf_b);
  // 8. head (small fp32 GEMMs)
  {
    dim3 g((NCLSD + 127)/128, 1);
    gemm_f32<0><<<g, 256, 0, stream>>>(clsb, head_w, head_b, nullptr, feat, NB, NCLSD, DM);
    gemm_f32<2><<<g, 256, 0, stream>>>(feat, fc1_w, fc1_b, nullptr, f1, NB, NCLSD, NCLSD);
    gemm_f32<0><<<dim3(1,1), 256, 0, stream>>>(f1, fc2_w, fc2_b, nullptr, out, NB, 2*NFR, NCLSD);
  }
}